// Round 1
// baseline (1055.987 us; speedup 1.0000x reference)
//
#include <hip/hip_runtime.h>

#define N_NODES  50000
#define N_EDGES  800000
#define NSC      32
#define XD       96
#define HID      128
#define MSG      256
#define LDA      264   // fallback kernel msg tile stride (bf16), 256+8 pad
#define LDH      136   // h tile stride (bf16 elems), 128+8 pad
#define LDXO     100   // x_out stride (fp32 elems), 96+4 pad
#define NBLK     196   // ceil(50000/256)

typedef __bf16 bf16x8 __attribute__((ext_vector_type(8)));
typedef float  f32x4  __attribute__((ext_vector_type(4)));
typedef unsigned short u16x8 __attribute__((ext_vector_type(8)));

__device__ __forceinline__ unsigned short f2bf(float f) {
    union { float f; unsigned int u; } v; v.f = f;
    unsigned int u = v.u;
    return (unsigned short)((u + 0x7FFFu + ((u >> 16) & 1u)) >> 16);
}
__device__ __forceinline__ float bflo(unsigned int u) {
    union { unsigned int u; float f; } v; v.u = u << 16; return v.f;
}
__device__ __forceinline__ float bfhi(unsigned int u) {
    union { unsigned int u; float f; } v; v.u = u & 0xffff0000u; return v.f;
}

// ---------------------------------------------------------------------------
// Weight prep: W1T[n][k] = bf16(W1[k][n]) (128x256), W2T[n][k] = bf16(W2[k][n])
__global__ void prep_weights(const float* __restrict__ W1, const float* __restrict__ W2,
                             unsigned short* __restrict__ W1T, unsigned short* __restrict__ W2T) {
    int i = blockIdx.x * 256 + threadIdx.x;
    if (i < 256 * 128) { int n = i >> 8; int k = i & 255; W1T[i] = f2bf(W1[k * 128 + n]); }
    if (i < 128 * 96)  { int n = i >> 7; int k = i & 127; W2T[i] = f2bf(W2[k * 96  + n]); }
}

// ---------------------------------------------------------------------------
// CSR build: fused histogram+rank -> block scan -> top scan -> fixup.
// pos0[e] = rank of edge e within its col segment; cnt[c] ends as degree(c).
__global__ void rank0_kernel(const int* __restrict__ eidx, int* __restrict__ cnt,
                             int* __restrict__ pos0) {
    int e = blockIdx.x * 256 + threadIdx.x;
    if (e < N_EDGES) pos0[e] = atomicAdd(&cnt[eidx[N_EDGES + e]], 1);
}

__global__ void scan_block(const int* __restrict__ cnt, int* __restrict__ start,
                           int* __restrict__ bsum) {
    __shared__ int tmp[256];
    const int t = threadIdx.x, i = blockIdx.x * 256 + t;
    int v = (i < N_NODES) ? cnt[i] : 0;
    tmp[t] = v; __syncthreads();
    #pragma unroll
    for (int off = 1; off < 256; off <<= 1) {
        int add = (t >= off) ? tmp[t - off] : 0;
        __syncthreads();
        tmp[t] += add;
        __syncthreads();
    }
    if (i < N_NODES) start[i] = tmp[t] - v;       // exclusive within block
    if (t == 255) bsum[blockIdx.x] = tmp[255];
}

__global__ void scan_top(const int* __restrict__ bsum, int* __restrict__ boff,
                         int* __restrict__ start) {
    __shared__ int tmp[256];
    const int t = threadIdx.x;
    int v = (t < NBLK) ? bsum[t] : 0;
    tmp[t] = v; __syncthreads();
    #pragma unroll
    for (int off = 1; off < 256; off <<= 1) {
        int add = (t >= off) ? tmp[t - off] : 0;
        __syncthreads();
        tmp[t] += add;
        __syncthreads();
    }
    if (t < NBLK) boff[t] = tmp[t] - v;
    if (t == 255) start[N_NODES] = tmp[255];      // = N_EDGES
}

__global__ void scan_fix(int* __restrict__ start, const int* __restrict__ boff) {
    const int t = threadIdx.x, i = blockIdx.x * 256 + t;
    if (i < N_NODES) start[i] += boff[blockIdx.x];
}

// ---------------------------------------------------------------------------
// Main fused kernel, SORTED path.
// LDS: ONE 32768B buffer time-shared A -> H -> XO (serial lifetimes, barriers
// between). A stored swizzled (byte ^= (row&7)<<4 on 16B chunks) instead of
// padded so the buffer is exactly 64*512B -> 5 blocks/CU.
// Stage 1 is branch-uniform: each thread owns 8 contiguous 16B chunks of its
// edge's 256-elem msg row; only two (base,rot?) segments per thread, rotate
// vs copy unified via identity-matrix select.
__global__ __launch_bounds__(256, 5)
void eq_main_sorted(const float* __restrict__ x_scalar, const float* __restrict__ x_rot,
                    const int* __restrict__ eidx, const float* __restrict__ dist,
                    const float* __restrict__ rot,
                    const unsigned short* __restrict__ W1T, const float* __restrict__ b1,
                    const unsigned short* __restrict__ W2T, const float* __restrict__ b2,
                    const int* __restrict__ start, const int* __restrict__ pos0,
                    unsigned int* __restrict__ msg)
{
    __shared__ union {
        unsigned char  B[64 * 512];      // bf16 A tile, swizzled      (32768B)
        unsigned short H[64 * LDH];      // GEMM1 out, after A is dead (17408B)
        float          XO[64 * LDXO];    // GEMM2 out, after H is dead (25600B)
    } uS;

    const int tid = threadIdx.x;
    const int e0  = blockIdx.x * 64;
    const int eL  = tid >> 2, p = tid & 3;
    const int e   = e0 + eL;             // grid is exactly N_EDGES/64: always valid

    const int r  = eidx[e];
    const int c  = eidx[N_EDGES + e];
    const int pe = start[c] + pos0[e];   // absolute sorted slot, carried to stage 4

    // ---------------- stage 1: uniform build of 64x256 bf16 msg tile --------
    {
        float rb[16];
        {
            const float4* rp = (const float4*)(rot + (size_t)e * 16);
            #pragma unroll
            for (int i = 0; i < 4; ++i) ((float4*)rb)[i] = rp[i];
        }
        // thread (eL,p) owns chunks ci = p*8 + i, i=0..7 (8 bf16 each).
        // Segment map: [0,4) sc[c] | [4,12) rot(xr[c]) | [12,16) sc[r]
        //              | [16,24) rot(xr[r]) | [24,32) dist[e]
        const float *baseA, *baseB; bool rotA, rotB;
        if (p == 0)      { baseA = x_scalar + (size_t)c * NSC;     rotA = false;
                           baseB = x_rot    + (size_t)c * 64;      rotB = true;  }
        else if (p == 1) { baseA = x_rot    + (size_t)c * 64 + 32; rotA = true;
                           baseB = x_scalar + (size_t)r * NSC;     rotB = false; }
        else if (p == 2) { baseA = x_rot    + (size_t)r * 64;      rotA = true;
                           baseB = x_rot    + (size_t)r * 64 + 32; rotB = true;  }
        else             { baseA = dist     + (size_t)e * 64;      rotA = false;
                           baseB = dist     + (size_t)e * 64 + 32; rotB = false; }

        #pragma unroll
        for (int i = 0; i < 8; ++i) {
            const float* src  = (i < 4) ? (baseA + i * 8) : (baseB + (i - 4) * 8);
            const bool  isrot = (i < 4) ? rotA : rotB;
            float4 v0 = ((const float4*)src)[0], v1 = ((const float4*)src)[1];
            float x[8] = { v0.x, v0.y, v0.z, v0.w, v1.x, v1.y, v1.z, v1.w };
            u16x8 t;
            #pragma unroll
            for (int k = 0; k < 4; ++k) {
                float a0 = x[2 * k], a1 = x[2 * k + 1];
                float r0 = a0 * rb[4 * k]     + a1 * rb[4 * k + 1];
                float r1 = a0 * rb[4 * k + 2] + a1 * rb[4 * k + 3];
                t[2 * k]     = f2bf(isrot ? r0 : a0);
                t[2 * k + 1] = f2bf(isrot ? r1 : a1);
            }
            const int ci = p * 8 + i;
            *(u16x8*)&uS.B[(eL << 9) + ((ci * 16) ^ ((eL & 7) << 4))] = t;
        }
    }
    __syncthreads();

    // ---------------- stage 2: GEMM1  msg(64x256) @ W1(256x128) -------------
    const int lane = tid & 63, wave = tid >> 6;
    const int lrow = lane & 15, quad = lane >> 4;
    const int m0 = wave * 16;

    {
        f32x4 acc[8];
        #pragma unroll
        for (int j = 0; j < 8; ++j) acc[j] = (f32x4){0.f, 0.f, 0.f, 0.f};
        #pragma unroll
        for (int kk = 0; kk < 8; ++kk) {
            bf16x8 a = *(const bf16x8*)&uS.B[((m0 + lrow) << 9) +
                                             ((kk * 64 + quad * 16) ^ ((lrow & 7) << 4))];
            const unsigned short* wb = W1T + (size_t)lrow * 256 + kk * 32 + quad * 8;
            #pragma unroll
            for (int j = 0; j < 8; ++j) {
                bf16x8 b = *(const bf16x8*)(wb + j * 16 * 256);
                acc[j] = __builtin_amdgcn_mfma_f32_16x16x32_bf16(a, b, acc[j], 0, 0, 0);
            }
        }
        __syncthreads();                 // all A reads done -> buffer reusable
        #pragma unroll
        for (int j = 0; j < 8; ++j) {
            const int n = j * 16 + lrow;
            const float bv = b1[n];      // global, L1-cached
            #pragma unroll
            for (int rr = 0; rr < 4; ++rr) {
                const int m = m0 + quad * 4 + rr;
                float v = acc[j][rr] + bv;
                float hv = v / (1.0f + __expf(-v));
                uS.H[m * LDH + n] = f2bf(hv);
            }
        }
    }
    __syncthreads();

    // ---------------- stage 3: GEMM2  h(64x128) @ W2(128x96) ----------------
    {
        f32x4 acc2[6];
        #pragma unroll
        for (int j = 0; j < 6; ++j) acc2[j] = (f32x4){0.f, 0.f, 0.f, 0.f};
        #pragma unroll
        for (int kk = 0; kk < 4; ++kk) {
            bf16x8 a = *(const bf16x8*)&uS.H[(m0 + lrow) * LDH + kk * 32 + quad * 8];
            const unsigned short* wb = W2T + (size_t)lrow * 128 + kk * 32 + quad * 8;
            #pragma unroll
            for (int j = 0; j < 6; ++j) {
                bf16x8 b = *(const bf16x8*)(wb + j * 16 * 128);
                acc2[j] = __builtin_amdgcn_mfma_f32_16x16x32_bf16(a, b, acc2[j], 0, 0, 0);
            }
        }
        __syncthreads();                 // all H reads done -> buffer reusable
        #pragma unroll
        for (int j = 0; j < 6; ++j) {
            const int n = j * 16 + lrow;
            const float bv = b2[n];
            #pragma unroll
            for (int rr = 0; rr < 4; ++rr) {
                const int m = m0 + quad * 4 + rr;
                uS.XO[m * LDXO + n] = acc2[j][rr] + bv;
            }
        }
    }
    __syncthreads();

    // ---------------- stage 4: forward-rotate + emit sorted bf16 row --------
    {
        float rb[16];
        {
            const float4* rp = (const float4*)(rot + (size_t)e * 16);   // L2 hit
            #pragma unroll
            for (int i = 0; i < 4; ++i) ((float4*)rb)[i] = rp[i];
        }
        const float* xo = &uS.XO[eL * LDXO];
        unsigned int buf[12];
        #pragma unroll
        for (int q = 0; q < 12; ++q) {
            const int i = p * 24 + 2 * q;
            float v0 = xo[i], v1 = xo[i + 1];
            if (i >= NSC) {
                const int k = ((i - NSC) >> 1) & 3;
                float a0 = v0, a1 = v1;
                v0 = a0 * rb[4 * k + 0] + a1 * rb[4 * k + 2];
                v1 = a0 * rb[4 * k + 1] + a1 * rb[4 * k + 3];
            }
            buf[q] = (unsigned int)f2bf(v0) | ((unsigned int)f2bf(v1) << 16);
        }
        unsigned int* mrow = msg + (size_t)pe * 48 + p * 12;
        *(uint4*)(mrow + 0) = *(uint4*)(buf + 0);
        *(uint4*)(mrow + 4) = *(uint4*)(buf + 4);
        *(uint4*)(mrow + 8) = *(uint4*)(buf + 8);
    }
}

// ---------------------------------------------------------------------------
// Fallback (atomic scatter) kernel — original structure, only used when the
// workspace is too small for the sorted path. Occupancy here is irrelevant.
__global__ __launch_bounds__(256, 2)
void eq_main_atomic(const float* __restrict__ x_scalar, const float* __restrict__ x_rot,
                    const int* __restrict__ eidx, const float* __restrict__ dist,
                    const float* __restrict__ rot,
                    const unsigned short* __restrict__ W1T, const float* __restrict__ b1,
                    const unsigned short* __restrict__ W2T, const float* __restrict__ b2,
                    float* __restrict__ out_scalar, float* __restrict__ out_rot)
{
    __shared__ union { unsigned short A[64 * LDA]; float XO[64 * LDXO]; } uA;
    __shared__ unsigned short H[64 * LDH];
    __shared__ int colidx[64];
    __shared__ float b1s[HID];
    __shared__ float b2s[XD];

    const int tid = threadIdx.x;
    const int e0  = blockIdx.x * 64;

    if (tid < HID) b1s[tid] = b1[tid];
    if (tid < XD)  b2s[tid] = b2[tid];

    {
        const int eL = tid >> 2, p = tid & 3;
        const int e  = e0 + eL;
        if (e < N_EDGES) {
            const int r = eidx[e];
            const int c = eidx[N_EDGES + e];
            if (p == 0) colidx[eL] = c;
            unsigned short* dst = &uA.A[eL * LDA];
            float rb[16];
            {
                const float4* rp = (const float4*)(rot + (size_t)e * 16);
                #pragma unroll
                for (int i = 0; i < 4; ++i) ((float4*)rb)[i] = rp[i];
            }
            const float *baseA, *baseB; bool rotA, rotB;
            if (p == 0)      { baseA = x_scalar + (size_t)c * NSC;     rotA = false;
                               baseB = x_rot    + (size_t)c * 64;      rotB = true;  }
            else if (p == 1) { baseA = x_rot    + (size_t)c * 64 + 32; rotA = true;
                               baseB = x_scalar + (size_t)r * NSC;     rotB = false; }
            else if (p == 2) { baseA = x_rot    + (size_t)r * 64;      rotA = true;
                               baseB = x_rot    + (size_t)r * 64 + 32; rotB = true;  }
            else             { baseA = dist     + (size_t)e * 64;      rotA = false;
                               baseB = dist     + (size_t)e * 64 + 32; rotB = false; }
            #pragma unroll
            for (int i = 0; i < 8; ++i) {
                const float* src  = (i < 4) ? (baseA + i * 8) : (baseB + (i - 4) * 8);
                const bool  isrot = (i < 4) ? rotA : rotB;
                float4 v0 = ((const float4*)src)[0], v1 = ((const float4*)src)[1];
                float x[8] = { v0.x, v0.y, v0.z, v0.w, v1.x, v1.y, v1.z, v1.w };
                u16x8 t;
                #pragma unroll
                for (int k = 0; k < 4; ++k) {
                    float a0 = x[2 * k], a1 = x[2 * k + 1];
                    float r0 = a0 * rb[4 * k]     + a1 * rb[4 * k + 1];
                    float r1 = a0 * rb[4 * k + 2] + a1 * rb[4 * k + 3];
                    t[2 * k]     = f2bf(isrot ? r0 : a0);
                    t[2 * k + 1] = f2bf(isrot ? r1 : a1);
                }
                *(u16x8*)(dst + (p * 8 + i) * 8) = t;
            }
        }
    }
    __syncthreads();

    const int lane = tid & 63, wave = tid >> 6;
    const int lrow = lane & 15, quad = lane >> 4;
    const int m0 = wave * 16;

    {
        f32x4 acc[8];
        #pragma unroll
        for (int j = 0; j < 8; ++j) acc[j] = (f32x4){0.f, 0.f, 0.f, 0.f};
        #pragma unroll
        for (int kk = 0; kk < 8; ++kk) {
            bf16x8 a = *(const bf16x8*)&uA.A[(m0 + lrow) * LDA + kk * 32 + quad * 8];
            const unsigned short* wb = W1T + (size_t)lrow * 256 + kk * 32 + quad * 8;
            #pragma unroll
            for (int j = 0; j < 8; ++j) {
                bf16x8 b = *(const bf16x8*)(wb + j * 16 * 256);
                acc[j] = __builtin_amdgcn_mfma_f32_16x16x32_bf16(a, b, acc[j], 0, 0, 0);
            }
        }
        #pragma unroll
        for (int j = 0; j < 8; ++j) {
            const int n = j * 16 + lrow;
            const float bv = b1s[n];
            #pragma unroll
            for (int rr = 0; rr < 4; ++rr) {
                const int m = m0 + quad * 4 + rr;
                float v = acc[j][rr] + bv;
                float hv = v / (1.0f + __expf(-v));
                H[m * LDH + n] = f2bf(hv);
            }
        }
    }
    __syncthreads();

    {
        f32x4 acc2[6];
        #pragma unroll
        for (int j = 0; j < 6; ++j) acc2[j] = (f32x4){0.f, 0.f, 0.f, 0.f};
        #pragma unroll
        for (int kk = 0; kk < 4; ++kk) {
            bf16x8 a = *(const bf16x8*)&H[(m0 + lrow) * LDH + kk * 32 + quad * 8];
            const unsigned short* wb = W2T + (size_t)lrow * 128 + kk * 32 + quad * 8;
            #pragma unroll
            for (int j = 0; j < 6; ++j) {
                bf16x8 b = *(const bf16x8*)(wb + j * 16 * 128);
                acc2[j] = __builtin_amdgcn_mfma_f32_16x16x32_bf16(a, b, acc2[j], 0, 0, 0);
            }
        }
        #pragma unroll
        for (int j = 0; j < 6; ++j) {
            const int n = j * 16 + lrow;
            const float bv = b2s[n];
            #pragma unroll
            for (int rr = 0; rr < 4; ++rr) {
                const int m = m0 + quad * 4 + rr;
                float v = acc2[j][rr] + bv;
                if (j < 2) {
                    if (e0 + m < N_EDGES)
                        atomicAdd(&out_scalar[(size_t)colidx[m] * NSC + n], v);
                } else {
                    uA.XO[m * LDXO + (n - NSC)] = v;
                }
            }
        }
    }
    __syncthreads();

    {
        const int eL = tid >> 2, p = tid & 3;
        const int e  = e0 + eL;
        if (e < N_EDGES) {
            float rb[16];
            {
                const float4* rp = (const float4*)(rot + (size_t)e * 16);
                #pragma unroll
                for (int i = 0; i < 4; ++i) ((float4*)rb)[i] = rp[i];
            }
            const int c = colidx[eL];
            const float* xo = &uA.XO[eL * LDXO];
            float* outp = out_rot + (size_t)c * 64;
            #pragma unroll
            for (int jj = 0; jj < 2; ++jj) {
                const int j = 2 * p + jj;
                #pragma unroll
                for (int k = 0; k < 4; ++k) {
                    float a0 = xo[j * 8 + k * 2], a1 = xo[j * 8 + k * 2 + 1];
                    atomicAdd(&outp[j * 8 + k * 2 + 0], a0 * rb[4 * k + 0] + a1 * rb[4 * k + 2]);
                    atomicAdd(&outp[j * 8 + k * 2 + 1], a0 * rb[4 * k + 1] + a1 * rb[4 * k + 3]);
                }
            }
        }
    }
}

// ---------------------------------------------------------------------------
// Gather: one wave per node, stream contiguous sorted message rows, fp32 acc.
__global__ __launch_bounds__(256)
void gather_kernel(const unsigned int* __restrict__ msg, const int* __restrict__ start,
                   float* __restrict__ out_scalar, float* __restrict__ out_rot) {
    const int wave = threadIdx.x >> 6, lane = threadIdx.x & 63;
    const int n = blockIdx.x * 4 + wave;
    if (n >= N_NODES) return;
    const int s = start[n], e = start[n + 1];
    if (lane < 48) {
        float a0 = 0.f, a1 = 0.f;
        const unsigned int* p = msg + (size_t)s * 48 + lane;
        int i = s;
        for (; i + 1 < e; i += 2) {
            unsigned int u0 = p[0], u1 = p[48];
            p += 96;
            a0 += bflo(u0) + bflo(u1);
            a1 += bfhi(u0) + bfhi(u1);
        }
        if (i < e) { unsigned int u = p[0]; a0 += bflo(u); a1 += bfhi(u); }
        const int col = lane * 2;
        float2 r = make_float2(a0, a1);
        if (col < NSC) *(float2*)(out_scalar + (size_t)n * NSC + col) = r;
        else           *(float2*)(out_rot   + (size_t)n * 64 + (col - NSC)) = r;
    }
}

// ---------------------------------------------------------------------------
extern "C" void kernel_launch(void* const* d_in, const int* in_sizes, int n_in,
                              void* d_out, int out_size, void* d_ws, size_t ws_size,
                              hipStream_t stream) {
    const float* x_scalar = (const float*)d_in[0];
    const float* x_rot    = (const float*)d_in[1];
    const int*   eidx     = (const int*)d_in[2];
    const float* dist     = (const float*)d_in[3];
    const float* rot      = (const float*)d_in[4];
    const float* W1       = (const float*)d_in[5];
    const float* b1       = (const float*)d_in[6];
    const float* W2       = (const float*)d_in[7];
    const float* b2       = (const float*)d_in[8];
    float* out        = (float*)d_out;
    float* out_rot    = out + (size_t)N_NODES * NSC;

    // workspace bump allocator (256B aligned)
    uintptr_t base = (uintptr_t)d_ws;
    auto alloc = [&](size_t bytes) {
        uintptr_t p = base; base += (bytes + 255) & ~(size_t)255; return p;
    };
    unsigned short* W1T  = (unsigned short*)alloc(256 * 128 * 2);
    unsigned short* W2T  = (unsigned short*)alloc(128 * 96 * 2);
    int*            cnt  = (int*)alloc(N_NODES * 4);
    int*            start= (int*)alloc((N_NODES + 1) * 4);
    int*            bsum = (int*)alloc(NBLK * 4);
    int*            boff = (int*)alloc(NBLK * 4);
    int*            pos0 = (int*)alloc((size_t)N_EDGES * 4);
    unsigned int*   msg  = (unsigned int*)alloc((size_t)N_EDGES * 48 * 4);
    const size_t needed = base - (uintptr_t)d_ws;

    prep_weights<<<128, 256, 0, stream>>>(W1, W2, W1T, W2T);

    if (ws_size >= needed) {
        hipMemsetAsync(cnt, 0, N_NODES * 4, stream);
        rank0_kernel<<<N_EDGES / 256, 256, 0, stream>>>(eidx, cnt, pos0);
        scan_block<<<NBLK, 256, 0, stream>>>(cnt, start, bsum);
        scan_top<<<1, 256, 0, stream>>>(bsum, boff, start);
        scan_fix<<<NBLK, 256, 0, stream>>>(start, boff);
        eq_main_sorted<<<N_EDGES / 64, 256, 0, stream>>>(
            x_scalar, x_rot, eidx, dist, rot, W1T, b1, W2T, b2,
            start, pos0, msg);
        gather_kernel<<<(N_NODES + 3) / 4, 256, 0, stream>>>(msg, start, out, out_rot);
    } else {
        // fallback: atomic scatter
        hipMemsetAsync(d_out, 0, (size_t)out_size * sizeof(float), stream);
        eq_main_atomic<<<N_EDGES / 64, 256, 0, stream>>>(
            x_scalar, x_rot, eidx, dist, rot, W1T, b1, W2T, b2,
            out, out_rot);
    }
}

// Round 4
// 1043.767 us; speedup vs baseline: 1.0117x; 1.0117x over previous
//
#include <hip/hip_runtime.h>

#define N_NODES  50000
#define N_EDGES  800000
#define NSC      32
#define XD       96
#define HID      128
#define MSG      256
#define LDA      264   // fallback kernel msg tile stride (bf16), 256+8 pad
#define LDH      136   // h tile stride (bf16 elems), 128+8 pad
#define LDXO     100   // x_out stride (fp32 elems), 96+4 pad
#define NBLK     196   // ceil(50000/256)

typedef __bf16 bf16x8 __attribute__((ext_vector_type(8)));
typedef float  f32x4  __attribute__((ext_vector_type(4)));
typedef unsigned short u16x8 __attribute__((ext_vector_type(8)));

__device__ __forceinline__ unsigned short f2bf(float f) {
    union { float f; unsigned int u; } v; v.f = f;
    unsigned int u = v.u;
    return (unsigned short)((u + 0x7FFFu + ((u >> 16) & 1u)) >> 16);
}
__device__ __forceinline__ float bflo(unsigned int u) {
    union { unsigned int u; float f; } v; v.u = u << 16; return v.f;
}
__device__ __forceinline__ float bfhi(unsigned int u) {
    union { unsigned int u; float f; } v; v.u = u & 0xffff0000u; return v.f;
}

// ---------------------------------------------------------------------------
// Weight prep: W1T[n][k] = bf16(W1[k][n]) (128x256), W2T[n][k] = bf16(W2[k][n])
__global__ void prep_weights(const float* __restrict__ W1, const float* __restrict__ W2,
                             unsigned short* __restrict__ W1T, unsigned short* __restrict__ W2T) {
    int i = blockIdx.x * 256 + threadIdx.x;
    if (i < 256 * 128) { int n = i >> 8; int k = i & 255; W1T[i] = f2bf(W1[k * 128 + n]); }
    if (i < 128 * 96)  { int n = i >> 7; int k = i & 127; W2T[i] = f2bf(W2[k * 96  + n]); }
}

// ---------------------------------------------------------------------------
// CSR build: fused histogram+rank -> block scan -> top scan -> fixup -> scatter.
// pos0[e] = rank of edge e within its col segment; cnt[c] ends as degree(c).
__global__ void rank0_kernel(const int* __restrict__ eidx, int* __restrict__ cnt,
                             int* __restrict__ pos0) {
    int e = blockIdx.x * 256 + threadIdx.x;
    if (e < N_EDGES) pos0[e] = atomicAdd(&cnt[eidx[N_EDGES + e]], 1);
}

__global__ void scan_block(const int* __restrict__ cnt, int* __restrict__ start,
                           int* __restrict__ bsum) {
    __shared__ int tmp[256];
    const int t = threadIdx.x, i = blockIdx.x * 256 + t;
    int v = (i < N_NODES) ? cnt[i] : 0;
    tmp[t] = v; __syncthreads();
    #pragma unroll
    for (int off = 1; off < 256; off <<= 1) {
        int add = (t >= off) ? tmp[t - off] : 0;
        __syncthreads();
        tmp[t] += add;
        __syncthreads();
    }
    if (i < N_NODES) start[i] = tmp[t] - v;       // exclusive within block
    if (t == 255) bsum[blockIdx.x] = tmp[255];
}

__global__ void scan_top(const int* __restrict__ bsum, int* __restrict__ boff,
                         int* __restrict__ start) {
    __shared__ int tmp[256];
    const int t = threadIdx.x;
    int v = (t < NBLK) ? bsum[t] : 0;
    tmp[t] = v; __syncthreads();
    #pragma unroll
    for (int off = 1; off < 256; off <<= 1) {
        int add = (t >= off) ? tmp[t - off] : 0;
        __syncthreads();
        tmp[t] += add;
        __syncthreads();
    }
    if (t < NBLK) boff[t] = tmp[t] - v;
    if (t == 255) start[N_NODES] = tmp[255];      // = N_EDGES
}

__global__ void scan_fix(int* __restrict__ start, const int* __restrict__ boff) {
    const int t = threadIdx.x, i = blockIdx.x * 256 + t;
    if (i < N_NODES) start[i] += boff[blockIdx.x];
}

// Scatter edge ids (+ their endpoints) into sorted-by-col slot order.
// After this, slot s holds {e, r, c} and msg row s belongs to edge e.
__global__ void scatter_kernel(const int* __restrict__ eidx, const int* __restrict__ start,
                               const int* __restrict__ pos0, int4* __restrict__ srt) {
    int e = blockIdx.x * 256 + threadIdx.x;
    if (e < N_EDGES) {
        int r = eidx[e];
        int c = eidx[N_EDGES + e];
        int slot = start[c] + pos0[e];
        srt[slot] = make_int4(e, r, c, 0);
    }
}

// ---------------------------------------------------------------------------
// Main fused kernel, SORTED-ORDER path: block b processes sorted slots
// [64b, 64b+64). Within a block the ~64 edges share only a few distinct
// dst nodes c (avg degree 16) -> x_scalar[c]/x_rot[c] gathers are L1 hits,
// and msg rows are written contiguously (row index == slot).
// LDS: ONE 32768B buffer time-shared A -> H -> XO (serial lifetimes).
__global__ __launch_bounds__(256, 5)
void eq_main_sorted(const float* __restrict__ x_scalar, const float* __restrict__ x_rot,
                    const float* __restrict__ dist, const float* __restrict__ rot,
                    const unsigned short* __restrict__ W1T, const float* __restrict__ b1,
                    const unsigned short* __restrict__ W2T, const float* __restrict__ b2,
                    const int4* __restrict__ srt, unsigned int* __restrict__ msg)
{
    __shared__ union {
        unsigned char  B[64 * 512];      // bf16 A tile, swizzled      (32768B)
        unsigned short H[64 * LDH];      // GEMM1 out, after A is dead (17408B)
        float          XO[64 * LDXO];    // GEMM2 out, after H is dead (25600B)
    } uS;

    const int tid = threadIdx.x;
    const int s0  = blockIdx.x * 64;
    const int eL  = tid >> 2, p = tid & 3;
    const int slot = s0 + eL;            // grid is exactly N_EDGES/64: always valid

    const int4 erc = srt[slot];
    const int e = erc.x, r = erc.y, c = erc.z;

    // ---------------- stage 1: uniform build of 64x256 bf16 msg tile --------
    {
        float rb[16];
        {
            const float4* rp = (const float4*)(rot + (size_t)e * 16);
            #pragma unroll
            for (int i = 0; i < 4; ++i) ((float4*)rb)[i] = rp[i];
        }
        // thread (eL,p) owns chunks ci = p*8 + i, i=0..7 (8 bf16 each).
        // Segment map: [0,4) sc[c] | [4,12) rot(xr[c]) | [12,16) sc[r]
        //              | [16,24) rot(xr[r]) | [24,32) dist[e]
        const float *baseA, *baseB; bool rotA, rotB;
        if (p == 0)      { baseA = x_scalar + (size_t)c * NSC;     rotA = false;
                           baseB = x_rot    + (size_t)c * 64;      rotB = true;  }
        else if (p == 1) { baseA = x_rot    + (size_t)c * 64 + 32; rotA = true;
                           baseB = x_scalar + (size_t)r * NSC;     rotB = false; }
        else if (p == 2) { baseA = x_rot    + (size_t)r * 64;      rotA = true;
                           baseB = x_rot    + (size_t)r * 64 + 32; rotB = true;  }
        else             { baseA = dist     + (size_t)e * 64;      rotA = false;
                           baseB = dist     + (size_t)e * 64 + 32; rotB = false; }

        #pragma unroll
        for (int i = 0; i < 8; ++i) {
            const float* src  = (i < 4) ? (baseA + i * 8) : (baseB + (i - 4) * 8);
            const bool  isrot = (i < 4) ? rotA : rotB;
            float4 v0 = ((const float4*)src)[0], v1 = ((const float4*)src)[1];
            float x[8] = { v0.x, v0.y, v0.z, v0.w, v1.x, v1.y, v1.z, v1.w };
            u16x8 t;
            #pragma unroll
            for (int k = 0; k < 4; ++k) {
                float a0 = x[2 * k], a1 = x[2 * k + 1];
                float r0 = a0 * rb[4 * k]     + a1 * rb[4 * k + 1];
                float r1 = a0 * rb[4 * k + 2] + a1 * rb[4 * k + 3];
                t[2 * k]     = f2bf(isrot ? r0 : a0);
                t[2 * k + 1] = f2bf(isrot ? r1 : a1);
            }
            const int ci = p * 8 + i;
            *(u16x8*)&uS.B[(eL << 9) + ((ci * 16) ^ ((eL & 7) << 4))] = t;
        }
    }
    __syncthreads();

    // ---------------- stage 2: GEMM1  msg(64x256) @ W1(256x128) -------------
    const int lane = tid & 63, wave = tid >> 6;
    const int lrow = lane & 15, quad = lane >> 4;
    const int m0 = wave * 16;

    {
        f32x4 acc[8];
        #pragma unroll
        for (int j = 0; j < 8; ++j) acc[j] = (f32x4){0.f, 0.f, 0.f, 0.f};
        #pragma unroll
        for (int kk = 0; kk < 8; ++kk) {
            bf16x8 a = *(const bf16x8*)&uS.B[((m0 + lrow) << 9) +
                                             ((kk * 64 + quad * 16) ^ ((lrow & 7) << 4))];
            const unsigned short* wb = W1T + (size_t)lrow * 256 + kk * 32 + quad * 8;
            #pragma unroll
            for (int j = 0; j < 8; ++j) {
                bf16x8 b = *(const bf16x8*)(wb + j * 16 * 256);
                acc[j] = __builtin_amdgcn_mfma_f32_16x16x32_bf16(a, b, acc[j], 0, 0, 0);
            }
        }
        __syncthreads();                 // all A reads done -> buffer reusable
        #pragma unroll
        for (int j = 0; j < 8; ++j) {
            const int n = j * 16 + lrow;
            const float bv = b1[n];      // global, L1-cached
            #pragma unroll
            for (int rr = 0; rr < 4; ++rr) {
                const int m = m0 + quad * 4 + rr;
                float v = acc[j][rr] + bv;
                float hv = v / (1.0f + __expf(-v));
                uS.H[m * LDH + n] = f2bf(hv);
            }
        }
    }
    __syncthreads();

    // ---------------- stage 3: GEMM2  h(64x128) @ W2(128x96) ----------------
    {
        f32x4 acc2[6];
        #pragma unroll
        for (int j = 0; j < 6; ++j) acc2[j] = (f32x4){0.f, 0.f, 0.f, 0.f};
        #pragma unroll
        for (int kk = 0; kk < 4; ++kk) {
            bf16x8 a = *(const bf16x8*)&uS.H[(m0 + lrow) * LDH + kk * 32 + quad * 8];
            const unsigned short* wb = W2T + (size_t)lrow * 128 + kk * 32 + quad * 8;
            #pragma unroll
            for (int j = 0; j < 6; ++j) {
                bf16x8 b = *(const bf16x8*)(wb + j * 16 * 128);
                acc2[j] = __builtin_amdgcn_mfma_f32_16x16x32_bf16(a, b, acc2[j], 0, 0, 0);
            }
        }
        __syncthreads();                 // all H reads done -> buffer reusable
        #pragma unroll
        for (int j = 0; j < 6; ++j) {
            const int n = j * 16 + lrow;
            const float bv = b2[n];
            #pragma unroll
            for (int rr = 0; rr < 4; ++rr) {
                const int m = m0 + quad * 4 + rr;
                uS.XO[m * LDXO + n] = acc2[j][rr] + bv;
            }
        }
    }
    __syncthreads();

    // ---------------- stage 4: forward-rotate + emit sorted bf16 row --------
    {
        float rb[16];
        {
            const float4* rp = (const float4*)(rot + (size_t)e * 16);   // L1 hit
            #pragma unroll
            for (int i = 0; i < 4; ++i) ((float4*)rb)[i] = rp[i];
        }
        const float* xo = &uS.XO[eL * LDXO];
        unsigned int buf[12];
        #pragma unroll
        for (int q = 0; q < 12; ++q) {
            const int i = p * 24 + 2 * q;
            float v0 = xo[i], v1 = xo[i + 1];
            if (i >= NSC) {
                const int k = ((i - NSC) >> 1) & 3;
                float a0 = v0, a1 = v1;
                v0 = a0 * rb[4 * k + 0] + a1 * rb[4 * k + 2];
                v1 = a0 * rb[4 * k + 1] + a1 * rb[4 * k + 3];
            }
            buf[q] = (unsigned int)f2bf(v0) | ((unsigned int)f2bf(v1) << 16);
        }
        unsigned int* mrow = msg + (size_t)slot * 48 + p * 12;   // contiguous!
        *(uint4*)(mrow + 0) = *(uint4*)(buf + 0);
        *(uint4*)(mrow + 4) = *(uint4*)(buf + 4);
        *(uint4*)(mrow + 8) = *(uint4*)(buf + 8);
    }
}

// ---------------------------------------------------------------------------
// Fallback (atomic scatter) kernel — only used when the workspace is too
// small for the sorted path.
__global__ __launch_bounds__(256, 2)
void eq_main_atomic(const float* __restrict__ x_scalar, const float* __restrict__ x_rot,
                    const int* __restrict__ eidx, const float* __restrict__ dist,
                    const float* __restrict__ rot,
                    const unsigned short* __restrict__ W1T, const float* __restrict__ b1,
                    const unsigned short* __restrict__ W2T, const float* __restrict__ b2,
                    float* __restrict__ out_scalar, float* __restrict__ out_rot)
{
    __shared__ union { unsigned short A[64 * LDA]; float XO[64 * LDXO]; } uA;
    __shared__ unsigned short H[64 * LDH];
    __shared__ int colidx[64];
    __shared__ float b1s[HID];
    __shared__ float b2s[XD];

    const int tid = threadIdx.x;
    const int e0  = blockIdx.x * 64;

    if (tid < HID) b1s[tid] = b1[tid];
    if (tid < XD)  b2s[tid] = b2[tid];

    {
        const int eL = tid >> 2, p = tid & 3;
        const int e  = e0 + eL;
        if (e < N_EDGES) {
            const int r = eidx[e];
            const int c = eidx[N_EDGES + e];
            if (p == 0) colidx[eL] = c;
            unsigned short* dst = &uA.A[eL * LDA];
            float rb[16];
            {
                const float4* rp = (const float4*)(rot + (size_t)e * 16);
                #pragma unroll
                for (int i = 0; i < 4; ++i) ((float4*)rb)[i] = rp[i];
            }
            const float *baseA, *baseB; bool rotA, rotB;
            if (p == 0)      { baseA = x_scalar + (size_t)c * NSC;     rotA = false;
                               baseB = x_rot    + (size_t)c * 64;      rotB = true;  }
            else if (p == 1) { baseA = x_rot    + (size_t)c * 64 + 32; rotA = true;
                               baseB = x_scalar + (size_t)r * NSC;     rotB = false; }
            else if (p == 2) { baseA = x_rot    + (size_t)r * 64;      rotA = true;
                               baseB = x_rot    + (size_t)r * 64 + 32; rotB = true;  }
            else             { baseA = dist     + (size_t)e * 64;      rotA = false;
                               baseB = dist     + (size_t)e * 64 + 32; rotB = false; }
            #pragma unroll
            for (int i = 0; i < 8; ++i) {
                const float* src  = (i < 4) ? (baseA + i * 8) : (baseB + (i - 4) * 8);
                const bool  isrot = (i < 4) ? rotA : rotB;
                float4 v0 = ((const float4*)src)[0], v1 = ((const float4*)src)[1];
                float x[8] = { v0.x, v0.y, v0.z, v0.w, v1.x, v1.y, v1.z, v1.w };
                u16x8 t;
                #pragma unroll
                for (int k = 0; k < 4; ++k) {
                    float a0 = x[2 * k], a1 = x[2 * k + 1];
                    float r0 = a0 * rb[4 * k]     + a1 * rb[4 * k + 1];
                    float r1 = a0 * rb[4 * k + 2] + a1 * rb[4 * k + 3];
                    t[2 * k]     = f2bf(isrot ? r0 : a0);
                    t[2 * k + 1] = f2bf(isrot ? r1 : a1);
                }
                *(u16x8*)(dst + (p * 8 + i) * 8) = t;
            }
        }
    }
    __syncthreads();

    const int lane = tid & 63, wave = tid >> 6;
    const int lrow = lane & 15, quad = lane >> 4;
    const int m0 = wave * 16;

    {
        f32x4 acc[8];
        #pragma unroll
        for (int j = 0; j < 8; ++j) acc[j] = (f32x4){0.f, 0.f, 0.f, 0.f};
        #pragma unroll
        for (int kk = 0; kk < 8; ++kk) {
            bf16x8 a = *(const bf16x8*)&uA.A[(m0 + lrow) * LDA + kk * 32 + quad * 8];
            const unsigned short* wb = W1T + (size_t)lrow * 256 + kk * 32 + quad * 8;
            #pragma unroll
            for (int j = 0; j < 8; ++j) {
                bf16x8 b = *(const bf16x8*)(wb + j * 16 * 256);
                acc[j] = __builtin_amdgcn_mfma_f32_16x16x32_bf16(a, b, acc[j], 0, 0, 0);
            }
        }
        #pragma unroll
        for (int j = 0; j < 8; ++j) {
            const int n = j * 16 + lrow;
            const float bv = b1s[n];
            #pragma unroll
            for (int rr = 0; rr < 4; ++rr) {
                const int m = m0 + quad * 4 + rr;
                float v = acc[j][rr] + bv;
                float hv = v / (1.0f + __expf(-v));
                H[m * LDH + n] = f2bf(hv);
            }
        }
    }
    __syncthreads();

    {
        f32x4 acc2[6];
        #pragma unroll
        for (int j = 0; j < 6; ++j) acc2[j] = (f32x4){0.f, 0.f, 0.f, 0.f};
        #pragma unroll
        for (int kk = 0; kk < 4; ++kk) {
            bf16x8 a = *(const bf16x8*)&H[(m0 + lrow) * LDH + kk * 32 + quad * 8];
            const unsigned short* wb = W2T + (size_t)lrow * 128 + kk * 32 + quad * 8;
            #pragma unroll
            for (int j = 0; j < 6; ++j) {
                bf16x8 b = *(const bf16x8*)(wb + j * 16 * 128);
                acc2[j] = __builtin_amdgcn_mfma_f32_16x16x32_bf16(a, b, acc2[j], 0, 0, 0);
            }
        }
        #pragma unroll
        for (int j = 0; j < 6; ++j) {
            const int n = j * 16 + lrow;
            const float bv = b2s[n];
            #pragma unroll
            for (int rr = 0; rr < 4; ++rr) {
                const int m = m0 + quad * 4 + rr;
                float v = acc2[j][rr] + bv;
                if (j < 2) {
                    if (e0 + m < N_EDGES)
                        atomicAdd(&out_scalar[(size_t)colidx[m] * NSC + n], v);
                } else {
                    uA.XO[m * LDXO + (n - NSC)] = v;
                }
            }
        }
    }
    __syncthreads();

    {
        const int eL = tid >> 2, p = tid & 3;
        const int e  = e0 + eL;
        if (e < N_EDGES) {
            float rb[16];
            {
                const float4* rp = (const float4*)(rot + (size_t)e * 16);
                #pragma unroll
                for (int i = 0; i < 4; ++i) ((float4*)rb)[i] = rp[i];
            }
            const int c = colidx[eL];
            const float* xo = &uA.XO[eL * LDXO];
            float* outp = out_rot + (size_t)c * 64;
            #pragma unroll
            for (int jj = 0; jj < 2; ++jj) {
                const int j = 2 * p + jj;
                #pragma unroll
                for (int k = 0; k < 4; ++k) {
                    float a0 = xo[j * 8 + k * 2], a1 = xo[j * 8 + k * 2 + 1];
                    atomicAdd(&outp[j * 8 + k * 2 + 0], a0 * rb[4 * k + 0] + a1 * rb[4 * k + 2]);
                    atomicAdd(&outp[j * 8 + k * 2 + 1], a0 * rb[4 * k + 1] + a1 * rb[4 * k + 3]);
                }
            }
        }
    }
}

// ---------------------------------------------------------------------------
// Gather: one wave per node, stream contiguous sorted message rows, fp32 acc.
__global__ __launch_bounds__(256)
void gather_kernel(const unsigned int* __restrict__ msg, const int* __restrict__ start,
                   float* __restrict__ out_scalar, float* __restrict__ out_rot) {
    const int wave = threadIdx.x >> 6, lane = threadIdx.x & 63;
    const int n = blockIdx.x * 4 + wave;
    if (n >= N_NODES) return;
    const int s = start[n], e = start[n + 1];
    if (lane < 48) {
        float a0 = 0.f, a1 = 0.f;
        const unsigned int* p = msg + (size_t)s * 48 + lane;
        int i = s;
        for (; i + 1 < e; i += 2) {
            unsigned int u0 = p[0], u1 = p[48];
            p += 96;
            a0 += bflo(u0) + bflo(u1);
            a1 += bfhi(u0) + bfhi(u1);
        }
        if (i < e) { unsigned int u = p[0]; a0 += bflo(u); a1 += bfhi(u); }
        const int col = lane * 2;
        float2 r = make_float2(a0, a1);
        if (col < NSC) *(float2*)(out_scalar + (size_t)n * NSC + col) = r;
        else           *(float2*)(out_rot   + (size_t)n * 64 + (col - NSC)) = r;
    }
}

// ---------------------------------------------------------------------------
extern "C" void kernel_launch(void* const* d_in, const int* in_sizes, int n_in,
                              void* d_out, int out_size, void* d_ws, size_t ws_size,
                              hipStream_t stream) {
    const float* x_scalar = (const float*)d_in[0];
    const float* x_rot    = (const float*)d_in[1];
    const int*   eidx     = (const int*)d_in[2];
    const float* dist     = (const float*)d_in[3];
    const float* rot      = (const float*)d_in[4];
    const float* W1       = (const float*)d_in[5];
    const float* b1       = (const float*)d_in[6];
    const float* W2       = (const float*)d_in[7];
    const float* b2       = (const float*)d_in[8];
    float* out        = (float*)d_out;
    float* out_rot    = out + (size_t)N_NODES * NSC;

    // workspace bump allocator (256B aligned)
    uintptr_t base = (uintptr_t)d_ws;
    auto alloc = [&](size_t bytes) {
        uintptr_t p = base; base += (bytes + 255) & ~(size_t)255; return p;
    };
    unsigned short* W1T  = (unsigned short*)alloc(256 * 128 * 2);
    unsigned short* W2T  = (unsigned short*)alloc(128 * 96 * 2);
    int*            cnt  = (int*)alloc(N_NODES * 4);
    int*            start= (int*)alloc((N_NODES + 1) * 4);
    int*            bsum = (int*)alloc(NBLK * 4);
    int*            boff = (int*)alloc(NBLK * 4);
    int*            pos0 = (int*)alloc((size_t)N_EDGES * 4);
    int4*           srt  = (int4*)alloc((size_t)N_EDGES * 16);
    unsigned int*   msg  = (unsigned int*)alloc((size_t)N_EDGES * 48 * 4);
    const size_t needed = base - (uintptr_t)d_ws;

    prep_weights<<<128, 256, 0, stream>>>(W1, W2, W1T, W2T);

    if (ws_size >= needed) {
        hipMemsetAsync(cnt, 0, N_NODES * 4, stream);
        rank0_kernel<<<N_EDGES / 256, 256, 0, stream>>>(eidx, cnt, pos0);
        scan_block<<<NBLK, 256, 0, stream>>>(cnt, start, bsum);
        scan_top<<<1, 256, 0, stream>>>(bsum, boff, start);
        scan_fix<<<NBLK, 256, 0, stream>>>(start, boff);
        scatter_kernel<<<N_EDGES / 256, 256, 0, stream>>>(eidx, start, pos0, srt);
        eq_main_sorted<<<N_EDGES / 64, 256, 0, stream>>>(
            x_scalar, x_rot, dist, rot, W1T, b1, W2T, b2, srt, msg);
        gather_kernel<<<(N_NODES + 3) / 4, 256, 0, stream>>>(msg, start, out, out_rot);
    } else {
        // fallback: atomic scatter
        hipMemsetAsync(d_out, 0, (size_t)out_size * sizeof(float), stream);
        eq_main_atomic<<<N_EDGES / 64, 256, 0, stream>>>(
            x_scalar, x_rot, eidx, dist, rot, W1T, b1, W2T, b2,
            out, out_rot);
    }
}

// Round 5
// 1017.962 us; speedup vs baseline: 1.0374x; 1.0253x over previous
//
#include <hip/hip_runtime.h>

#define N_NODES  50000
#define N_EDGES  800000
#define NSC      32
#define XD       96
#define HID      128
#define MSG      256
#define LDA      264   // fallback kernel msg tile stride (bf16), 256+8 pad
#define LDH      136   // h tile stride (bf16 elems), 128+8 pad
#define LDXO     100   // x_out stride (fp32 elems), 96+4 pad
#define NBLK     196   // ceil(50000/256)

typedef __bf16 bf16x8 __attribute__((ext_vector_type(8)));
typedef float  f32x4  __attribute__((ext_vector_type(4)));
typedef unsigned short u16x8 __attribute__((ext_vector_type(8)));

__device__ __forceinline__ unsigned short f2bf(float f) {
    union { float f; unsigned int u; } v; v.f = f;
    unsigned int u = v.u;
    return (unsigned short)((u + 0x7FFFu + ((u >> 16) & 1u)) >> 16);
}
__device__ __forceinline__ float bflo(unsigned int u) {
    union { unsigned int u; float f; } v; v.u = u << 16; return v.f;
}
__device__ __forceinline__ float bfhi(unsigned int u) {
    union { unsigned int u; float f; } v; v.u = u & 0xffff0000u; return v.f;
}

// ---------------------------------------------------------------------------
// Weight prep: W1T[n][k] = bf16(W1[k][n]) (128x256), W2T[n][k] = bf16(W2[k][n])
__global__ void prep_weights(const float* __restrict__ W1, const float* __restrict__ W2,
                             unsigned short* __restrict__ W1T, unsigned short* __restrict__ W2T) {
    int i = blockIdx.x * 256 + threadIdx.x;
    if (i < 256 * 128) { int n = i >> 8; int k = i & 255; W1T[i] = f2bf(W1[k * 128 + n]); }
    if (i < 128 * 96)  { int n = i >> 7; int k = i & 127; W2T[i] = f2bf(W2[k * 96  + n]); }
}

// ---------------------------------------------------------------------------
// CSR build: fused histogram+rank -> block scan -> top scan -> fixup -> scatter.
// pos0[e] = rank of edge e within its col segment; cnt[c] ends as degree(c).
__global__ void rank0_kernel(const int* __restrict__ eidx, int* __restrict__ cnt,
                             int* __restrict__ pos0) {
    int e = blockIdx.x * 256 + threadIdx.x;
    if (e < N_EDGES) pos0[e] = atomicAdd(&cnt[eidx[N_EDGES + e]], 1);
}

__global__ void scan_block(const int* __restrict__ cnt, int* __restrict__ start,
                           int* __restrict__ bsum) {
    __shared__ int tmp[256];
    const int t = threadIdx.x, i = blockIdx.x * 256 + t;
    int v = (i < N_NODES) ? cnt[i] : 0;
    tmp[t] = v; __syncthreads();
    #pragma unroll
    for (int off = 1; off < 256; off <<= 1) {
        int add = (t >= off) ? tmp[t - off] : 0;
        __syncthreads();
        tmp[t] += add;
        __syncthreads();
    }
    if (i < N_NODES) start[i] = tmp[t] - v;       // exclusive within block
    if (t == 255) bsum[blockIdx.x] = tmp[255];
}

__global__ void scan_top(const int* __restrict__ bsum, int* __restrict__ boff,
                         int* __restrict__ start) {
    __shared__ int tmp[256];
    const int t = threadIdx.x;
    int v = (t < NBLK) ? bsum[t] : 0;
    tmp[t] = v; __syncthreads();
    #pragma unroll
    for (int off = 1; off < 256; off <<= 1) {
        int add = (t >= off) ? tmp[t - off] : 0;
        __syncthreads();
        tmp[t] += add;
        __syncthreads();
    }
    if (t < NBLK) boff[t] = tmp[t] - v;
    if (t == 255) start[N_NODES] = tmp[255];      // = N_EDGES
}

__global__ void scan_fix(int* __restrict__ start, const int* __restrict__ boff) {
    const int t = threadIdx.x, i = blockIdx.x * 256 + t;
    if (i < N_NODES) start[i] += boff[blockIdx.x];
}

// Scatter edge ids (+ their endpoints) into sorted-by-col slot order.
// After this, slot s holds {e, r, c} and msg row s belongs to edge e.
__global__ void scatter_kernel(const int* __restrict__ eidx, const int* __restrict__ start,
                               const int* __restrict__ pos0, int4* __restrict__ srt) {
    int e = blockIdx.x * 256 + threadIdx.x;
    if (e < N_EDGES) {
        int r = eidx[e];
        int c = eidx[N_EDGES + e];
        int slot = start[c] + pos0[e];
        srt[slot] = make_int4(e, r, c, 0);
    }
}

// ---------------------------------------------------------------------------
// Main fused kernel, SINGLE-WAVE blocks: one 64-thread wave handles 16 sorted
// slots. Rationale (R4 counters): all pipes <15% busy, time = exposed memory
// latency behind barrier-locked 4-wave blocks (~3.6 independent streams/CU).
// At 8 KiB LDS per 1-wave workgroup, ~16-20 INDEPENDENT waves fit per CU; a
// 1-wave __syncthreads never blocks on other waves, so each wave's stalls are
// hidden by the others. Per-edge work and weight L2 traffic are unchanged.
// LDS: ONE 8192B buffer time-shared A -> H -> XO (serial lifetimes).
__global__ __launch_bounds__(64, 8)
void eq_main_sorted(const float* __restrict__ x_scalar, const float* __restrict__ x_rot,
                    const float* __restrict__ dist, const float* __restrict__ rot,
                    const unsigned short* __restrict__ W1T, const float* __restrict__ b1,
                    const unsigned short* __restrict__ W2T, const float* __restrict__ b2,
                    const int4* __restrict__ srt, unsigned int* __restrict__ msg)
{
    __shared__ union {
        unsigned char  B[16 * 512];      // bf16 A tile, swizzled      (8192B)
        unsigned short H[16 * LDH];      // GEMM1 out, after A is dead (4352B)
        float          XO[16 * LDXO];    // GEMM2 out, after H is dead (6400B)
    } uS;

    const int tid = threadIdx.x;         // 0..63, one wave
    const int s0  = blockIdx.x * 16;
    const int eL  = tid >> 2, p = tid & 3;   // edge-local 0..15, quarter 0..3
    const int slot = s0 + eL;            // grid is exactly N_EDGES/16: always valid

    const int4 erc = srt[slot];
    const int e = erc.x, r = erc.y, c = erc.z;

    // ---------------- stage 1: uniform build of 16x256 bf16 msg tile --------
    {
        float rb[16];
        {
            const float4* rp = (const float4*)(rot + (size_t)e * 16);
            #pragma unroll
            for (int i = 0; i < 4; ++i) ((float4*)rb)[i] = rp[i];
        }
        // thread (eL,p) owns chunks ci = p*8 + i, i=0..7 (8 bf16 each).
        // Segment map: [0,4) sc[c] | [4,12) rot(xr[c]) | [12,16) sc[r]
        //              | [16,24) rot(xr[r]) | [24,32) dist[e]
        const float *baseA, *baseB; bool rotA, rotB;
        if (p == 0)      { baseA = x_scalar + (size_t)c * NSC;     rotA = false;
                           baseB = x_rot    + (size_t)c * 64;      rotB = true;  }
        else if (p == 1) { baseA = x_rot    + (size_t)c * 64 + 32; rotA = true;
                           baseB = x_scalar + (size_t)r * NSC;     rotB = false; }
        else if (p == 2) { baseA = x_rot    + (size_t)r * 64;      rotA = true;
                           baseB = x_rot    + (size_t)r * 64 + 32; rotB = true;  }
        else             { baseA = dist     + (size_t)e * 64;      rotA = false;
                           baseB = dist     + (size_t)e * 64 + 32; rotB = false; }

        #pragma unroll
        for (int i = 0; i < 8; ++i) {
            const float* src  = (i < 4) ? (baseA + i * 8) : (baseB + (i - 4) * 8);
            const bool  isrot = (i < 4) ? rotA : rotB;
            float4 v0 = ((const float4*)src)[0], v1 = ((const float4*)src)[1];
            float x[8] = { v0.x, v0.y, v0.z, v0.w, v1.x, v1.y, v1.z, v1.w };
            u16x8 t;
            #pragma unroll
            for (int k = 0; k < 4; ++k) {
                float a0 = x[2 * k], a1 = x[2 * k + 1];
                float r0 = a0 * rb[4 * k]     + a1 * rb[4 * k + 1];
                float r1 = a0 * rb[4 * k + 2] + a1 * rb[4 * k + 3];
                t[2 * k]     = f2bf(isrot ? r0 : a0);
                t[2 * k + 1] = f2bf(isrot ? r1 : a1);
            }
            const int ci = p * 8 + i;
            *(u16x8*)&uS.B[(eL << 9) + ((ci * 16) ^ ((eL & 7) << 4))] = t;
        }
    }
    __syncthreads();                     // single-wave: cheap (no cross-wave wait)

    // ---------------- stage 2: GEMM1  msg(16x256) @ W1(256x128) -------------
    const int lrow = tid & 15, quad = tid >> 4;

    {
        f32x4 acc[8];
        #pragma unroll
        for (int j = 0; j < 8; ++j) acc[j] = (f32x4){0.f, 0.f, 0.f, 0.f};
        #pragma unroll
        for (int kk = 0; kk < 8; ++kk) {
            bf16x8 a = *(const bf16x8*)&uS.B[(lrow << 9) +
                                             ((kk * 64 + quad * 16) ^ ((lrow & 7) << 4))];
            const unsigned short* wb = W1T + (size_t)lrow * 256 + kk * 32 + quad * 8;
            #pragma unroll
            for (int j = 0; j < 8; ++j) {
                bf16x8 b = *(const bf16x8*)(wb + j * 16 * 256);
                acc[j] = __builtin_amdgcn_mfma_f32_16x16x32_bf16(a, b, acc[j], 0, 0, 0);
            }
        }
        __syncthreads();                 // all A reads done -> buffer reusable
        #pragma unroll
        for (int j = 0; j < 8; ++j) {
            const int n = j * 16 + lrow;
            const float bv = b1[n];      // global, L1-cached
            #pragma unroll
            for (int rr = 0; rr < 4; ++rr) {
                const int m = quad * 4 + rr;
                float v = acc[j][rr] + bv;
                float hv = v / (1.0f + __expf(-v));
                uS.H[m * LDH + n] = f2bf(hv);
            }
        }
    }
    __syncthreads();

    // ---------------- stage 3: GEMM2  h(16x128) @ W2(128x96) ----------------
    {
        f32x4 acc2[6];
        #pragma unroll
        for (int j = 0; j < 6; ++j) acc2[j] = (f32x4){0.f, 0.f, 0.f, 0.f};
        #pragma unroll
        for (int kk = 0; kk < 4; ++kk) {
            bf16x8 a = *(const bf16x8*)&uS.H[lrow * LDH + kk * 32 + quad * 8];
            const unsigned short* wb = W2T + (size_t)lrow * 128 + kk * 32 + quad * 8;
            #pragma unroll
            for (int j = 0; j < 6; ++j) {
                bf16x8 b = *(const bf16x8*)(wb + j * 16 * 128);
                acc2[j] = __builtin_amdgcn_mfma_f32_16x16x32_bf16(a, b, acc2[j], 0, 0, 0);
            }
        }
        __syncthreads();                 // all H reads done -> buffer reusable
        #pragma unroll
        for (int j = 0; j < 6; ++j) {
            const int n = j * 16 + lrow;
            const float bv = b2[n];
            #pragma unroll
            for (int rr = 0; rr < 4; ++rr) {
                const int m = quad * 4 + rr;
                uS.XO[m * LDXO + n] = acc2[j][rr] + bv;
            }
        }
    }
    __syncthreads();

    // ---------------- stage 4: forward-rotate + emit sorted bf16 row --------
    {
        float rb[16];
        {
            const float4* rp = (const float4*)(rot + (size_t)e * 16);   // cache hit
            #pragma unroll
            for (int i = 0; i < 4; ++i) ((float4*)rb)[i] = rp[i];
        }
        const float* xo = &uS.XO[eL * LDXO];
        unsigned int buf[12];
        #pragma unroll
        for (int q = 0; q < 12; ++q) {
            const int i = p * 24 + 2 * q;
            float v0 = xo[i], v1 = xo[i + 1];
            if (i >= NSC) {
                const int k = ((i - NSC) >> 1) & 3;
                float a0 = v0, a1 = v1;
                v0 = a0 * rb[4 * k + 0] + a1 * rb[4 * k + 2];
                v1 = a0 * rb[4 * k + 1] + a1 * rb[4 * k + 3];
            }
            buf[q] = (unsigned int)f2bf(v0) | ((unsigned int)f2bf(v1) << 16);
        }
        unsigned int* mrow = msg + (size_t)slot * 48 + p * 12;   // contiguous!
        *(uint4*)(mrow + 0) = *(uint4*)(buf + 0);
        *(uint4*)(mrow + 4) = *(uint4*)(buf + 4);
        *(uint4*)(mrow + 8) = *(uint4*)(buf + 8);
    }
}

// ---------------------------------------------------------------------------
// Fallback (atomic scatter) kernel — only used when the workspace is too
// small for the sorted path.
__global__ __launch_bounds__(256, 2)
void eq_main_atomic(const float* __restrict__ x_scalar, const float* __restrict__ x_rot,
                    const int* __restrict__ eidx, const float* __restrict__ dist,
                    const float* __restrict__ rot,
                    const unsigned short* __restrict__ W1T, const float* __restrict__ b1,
                    const unsigned short* __restrict__ W2T, const float* __restrict__ b2,
                    float* __restrict__ out_scalar, float* __restrict__ out_rot)
{
    __shared__ union { unsigned short A[64 * LDA]; float XO[64 * LDXO]; } uA;
    __shared__ unsigned short H[64 * LDH];
    __shared__ int colidx[64];
    __shared__ float b1s[HID];
    __shared__ float b2s[XD];

    const int tid = threadIdx.x;
    const int e0  = blockIdx.x * 64;

    if (tid < HID) b1s[tid] = b1[tid];
    if (tid < XD)  b2s[tid] = b2[tid];

    {
        const int eL = tid >> 2, p = tid & 3;
        const int e  = e0 + eL;
        if (e < N_EDGES) {
            const int r = eidx[e];
            const int c = eidx[N_EDGES + e];
            if (p == 0) colidx[eL] = c;
            unsigned short* dst = &uA.A[eL * LDA];
            float rb[16];
            {
                const float4* rp = (const float4*)(rot + (size_t)e * 16);
                #pragma unroll
                for (int i = 0; i < 4; ++i) ((float4*)rb)[i] = rp[i];
            }
            const float *baseA, *baseB; bool rotA, rotB;
            if (p == 0)      { baseA = x_scalar + (size_t)c * NSC;     rotA = false;
                               baseB = x_rot    + (size_t)c * 64;      rotB = true;  }
            else if (p == 1) { baseA = x_rot    + (size_t)c * 64 + 32; rotA = true;
                               baseB = x_scalar + (size_t)r * NSC;     rotB = false; }
            else if (p == 2) { baseA = x_rot    + (size_t)r * 64;      rotA = true;
                               baseB = x_rot    + (size_t)r * 64 + 32; rotB = true;  }
            else             { baseA = dist     + (size_t)e * 64;      rotA = false;
                               baseB = dist     + (size_t)e * 64 + 32; rotB = false; }
            #pragma unroll
            for (int i = 0; i < 8; ++i) {
                const float* src  = (i < 4) ? (baseA + i * 8) : (baseB + (i - 4) * 8);
                const bool  isrot = (i < 4) ? rotA : rotB;
                float4 v0 = ((const float4*)src)[0], v1 = ((const float4*)src)[1];
                float x[8] = { v0.x, v0.y, v0.z, v0.w, v1.x, v1.y, v1.z, v1.w };
                u16x8 t;
                #pragma unroll
                for (int k = 0; k < 4; ++k) {
                    float a0 = x[2 * k], a1 = x[2 * k + 1];
                    float r0 = a0 * rb[4 * k]     + a1 * rb[4 * k + 1];
                    float r1 = a0 * rb[4 * k + 2] + a1 * rb[4 * k + 3];
                    t[2 * k]     = f2bf(isrot ? r0 : a0);
                    t[2 * k + 1] = f2bf(isrot ? r1 : a1);
                }
                *(u16x8*)(dst + (p * 8 + i) * 8) = t;
            }
        }
    }
    __syncthreads();

    const int lane = tid & 63, wave = tid >> 6;
    const int lrow = lane & 15, quad = lane >> 4;
    const int m0 = wave * 16;

    {
        f32x4 acc[8];
        #pragma unroll
        for (int j = 0; j < 8; ++j) acc[j] = (f32x4){0.f, 0.f, 0.f, 0.f};
        #pragma unroll
        for (int kk = 0; kk < 8; ++kk) {
            bf16x8 a = *(const bf16x8*)&uA.A[(m0 + lrow) * LDA + kk * 32 + quad * 8];
            const unsigned short* wb = W1T + (size_t)lrow * 256 + kk * 32 + quad * 8;
            #pragma unroll
            for (int j = 0; j < 8; ++j) {
                bf16x8 b = *(const bf16x8*)(wb + j * 16 * 256);
                acc[j] = __builtin_amdgcn_mfma_f32_16x16x32_bf16(a, b, acc[j], 0, 0, 0);
            }
        }
        #pragma unroll
        for (int j = 0; j < 8; ++j) {
            const int n = j * 16 + lrow;
            const float bv = b1s[n];
            #pragma unroll
            for (int rr = 0; rr < 4; ++rr) {
                const int m = m0 + quad * 4 + rr;
                float v = acc[j][rr] + bv;
                float hv = v / (1.0f + __expf(-v));
                H[m * LDH + n] = f2bf(hv);
            }
        }
    }
    __syncthreads();

    {
        f32x4 acc2[6];
        #pragma unroll
        for (int j = 0; j < 6; ++j) acc2[j] = (f32x4){0.f, 0.f, 0.f, 0.f};
        #pragma unroll
        for (int kk = 0; kk < 4; ++kk) {
            bf16x8 a = *(const bf16x8*)&H[(m0 + lrow) * LDH + kk * 32 + quad * 8];
            const unsigned short* wb = W2T + (size_t)lrow * 128 + kk * 32 + quad * 8;
            #pragma unroll
            for (int j = 0; j < 6; ++j) {
                bf16x8 b = *(const bf16x8*)(wb + j * 16 * 128);
                acc2[j] = __builtin_amdgcn_mfma_f32_16x16x32_bf16(a, b, acc2[j], 0, 0, 0);
            }
        }
        #pragma unroll
        for (int j = 0; j < 6; ++j) {
            const int n = j * 16 + lrow;
            const float bv = b2s[n];
            #pragma unroll
            for (int rr = 0; rr < 4; ++rr) {
                const int m = m0 + quad * 4 + rr;
                float v = acc2[j][rr] + bv;
                if (j < 2) {
                    if (e0 + m < N_EDGES)
                        atomicAdd(&out_scalar[(size_t)colidx[m] * NSC + n], v);
                } else {
                    uA.XO[m * LDXO + (n - NSC)] = v;
                }
            }
        }
    }
    __syncthreads();

    {
        const int eL = tid >> 2, p = tid & 3;
        const int e  = e0 + eL;
        if (e < N_EDGES) {
            float rb[16];
            {
                const float4* rp = (const float4*)(rot + (size_t)e * 16);
                #pragma unroll
                for (int i = 0; i < 4; ++i) ((float4*)rb)[i] = rp[i];
            }
            const int c = colidx[eL];
            const float* xo = &uA.XO[eL * LDXO];
            float* outp = out_rot + (size_t)c * 64;
            #pragma unroll
            for (int jj = 0; jj < 2; ++jj) {
                const int j = 2 * p + jj;
                #pragma unroll
                for (int k = 0; k < 4; ++k) {
                    float a0 = xo[j * 8 + k * 2], a1 = xo[j * 8 + k * 2 + 1];
                    atomicAdd(&outp[j * 8 + k * 2 + 0], a0 * rb[4 * k + 0] + a1 * rb[4 * k + 2]);
                    atomicAdd(&outp[j * 8 + k * 2 + 1], a0 * rb[4 * k + 1] + a1 * rb[4 * k + 3]);
                }
            }
        }
    }
}

// ---------------------------------------------------------------------------
// Gather: one wave per node, stream contiguous sorted message rows, fp32 acc.
__global__ __launch_bounds__(256)
void gather_kernel(const unsigned int* __restrict__ msg, const int* __restrict__ start,
                   float* __restrict__ out_scalar, float* __restrict__ out_rot) {
    const int wave = threadIdx.x >> 6, lane = threadIdx.x & 63;
    const int n = blockIdx.x * 4 + wave;
    if (n >= N_NODES) return;
    const int s = start[n], e = start[n + 1];
    if (lane < 48) {
        float a0 = 0.f, a1 = 0.f;
        const unsigned int* p = msg + (size_t)s * 48 + lane;
        int i = s;
        for (; i + 1 < e; i += 2) {
            unsigned int u0 = p[0], u1 = p[48];
            p += 96;
            a0 += bflo(u0) + bflo(u1);
            a1 += bfhi(u0) + bfhi(u1);
        }
        if (i < e) { unsigned int u = p[0]; a0 += bflo(u); a1 += bfhi(u); }
        const int col = lane * 2;
        float2 r = make_float2(a0, a1);
        if (col < NSC) *(float2*)(out_scalar + (size_t)n * NSC + col) = r;
        else           *(float2*)(out_rot   + (size_t)n * 64 + (col - NSC)) = r;
    }
}

// ---------------------------------------------------------------------------
extern "C" void kernel_launch(void* const* d_in, const int* in_sizes, int n_in,
                              void* d_out, int out_size, void* d_ws, size_t ws_size,
                              hipStream_t stream) {
    const float* x_scalar = (const float*)d_in[0];
    const float* x_rot    = (const float*)d_in[1];
    const int*   eidx     = (const int*)d_in[2];
    const float* dist     = (const float*)d_in[3];
    const float* rot      = (const float*)d_in[4];
    const float* W1       = (const float*)d_in[5];
    const float* b1       = (const float*)d_in[6];
    const float* W2       = (const float*)d_in[7];
    const float* b2       = (const float*)d_in[8];
    float* out        = (float*)d_out;
    float* out_rot    = out + (size_t)N_NODES * NSC;

    // workspace bump allocator (256B aligned)
    uintptr_t base = (uintptr_t)d_ws;
    auto alloc = [&](size_t bytes) {
        uintptr_t p = base; base += (bytes + 255) & ~(size_t)255; return p;
    };
    unsigned short* W1T  = (unsigned short*)alloc(256 * 128 * 2);
    unsigned short* W2T  = (unsigned short*)alloc(128 * 96 * 2);
    int*            cnt  = (int*)alloc(N_NODES * 4);
    int*            start= (int*)alloc((N_NODES + 1) * 4);
    int*            bsum = (int*)alloc(NBLK * 4);
    int*            boff = (int*)alloc(NBLK * 4);
    int*            pos0 = (int*)alloc((size_t)N_EDGES * 4);
    int4*           srt  = (int4*)alloc((size_t)N_EDGES * 16);
    unsigned int*   msg  = (unsigned int*)alloc((size_t)N_EDGES * 48 * 4);
    const size_t needed = base - (uintptr_t)d_ws;

    prep_weights<<<128, 256, 0, stream>>>(W1, W2, W1T, W2T);

    if (ws_size >= needed) {
        hipMemsetAsync(cnt, 0, N_NODES * 4, stream);
        rank0_kernel<<<N_EDGES / 256, 256, 0, stream>>>(eidx, cnt, pos0);
        scan_block<<<NBLK, 256, 0, stream>>>(cnt, start, bsum);
        scan_top<<<1, 256, 0, stream>>>(bsum, boff, start);
        scan_fix<<<NBLK, 256, 0, stream>>>(start, boff);
        scatter_kernel<<<N_EDGES / 256, 256, 0, stream>>>(eidx, start, pos0, srt);
        eq_main_sorted<<<N_EDGES / 16, 64, 0, stream>>>(
            x_scalar, x_rot, dist, rot, W1T, b1, W2T, b2, srt, msg);
        gather_kernel<<<(N_NODES + 3) / 4, 256, 0, stream>>>(msg, start, out, out_rot);
    } else {
        // fallback: atomic scatter
        hipMemsetAsync(d_out, 0, (size_t)out_size * sizeof(float), stream);
        eq_main_atomic<<<N_EDGES / 64, 256, 0, stream>>>(
            x_scalar, x_rot, eidx, dist, rot, W1T, b1, W2T, b2,
            out, out_rot);
    }
}

// Round 6
// 611.525 us; speedup vs baseline: 1.7268x; 1.6646x over previous
//
#include <hip/hip_runtime.h>

#define N_NODES  50000
#define N_EDGES  800000
#define NSC      32
#define XD       96
#define HID      128
#define MSG      256
#define LDH      136   // h tile stride (bf16 elems), 128+8 pad
#define LDXO     100   // x_out stride (fp32 elems), 96+4 pad
#define NBLK     196   // ceil(50000/256)
#define NTILES   50000 // N_EDGES / 16
#define TPW      25    // tiles per wave: 2048 waves * 25 >= 50000

typedef __bf16 bf16x8 __attribute__((ext_vector_type(8)));
typedef float  f32x4  __attribute__((ext_vector_type(4)));
typedef unsigned short u16x8 __attribute__((ext_vector_type(8)));

__device__ __forceinline__ unsigned short f2bf(float f) {
    union { float f; unsigned int u; } v; v.f = f;
    unsigned int u = v.u;
    return (unsigned short)((u + 0x7FFFu + ((u >> 16) & 1u)) >> 16);
}
__device__ __forceinline__ float bflo(unsigned int u) {
    union { unsigned int u; float f; } v; v.u = u << 16; return v.f;
}
__device__ __forceinline__ float bfhi(unsigned int u) {
    union { unsigned int u; float f; } v; v.u = u & 0xffff0000u; return v.f;
}

// Wave-local stage fence: order LDS ops of THIS wave (replaces __syncthreads
// in the barrier-free 8-independent-waves design). lgkmcnt(0) drains DS ops;
// memory clobber + sched_barrier stop compiler reordering across it.
#define WAVE_SYNC() do { \
    asm volatile("s_waitcnt lgkmcnt(0)" ::: "memory"); \
    __builtin_amdgcn_sched_barrier(0); \
} while (0)

// ---------------------------------------------------------------------------
// Weight prep, LDS-fragment order:
//  W1R[kt*1024 + n*8 + j] = bf16(W1[(kt*8+j)*128 + n])   kt in [0,32), n in [0,128)
//  W2R[kt*768  + n*8 + j] = bf16(W2[(kt*8+j)*96  + n])   kt in [0,16), n in [0,96)
// so a GEMM b-fragment (kt, n) is 8 contiguous bf16 -> linear LDS staging.
__global__ void prep_weights(const float* __restrict__ W1, const float* __restrict__ W2,
                             unsigned short* __restrict__ W1R, unsigned short* __restrict__ W2R) {
    int o = blockIdx.x * 256 + threadIdx.x;
    if (o < 32 * 128 * 8) {
        int j = o & 7, ch = o >> 3;
        int n = ch & 127, kt = ch >> 7;
        W1R[o] = f2bf(W1[(kt * 8 + j) * 128 + n]);
    }
    if (o < 16 * 96 * 8) {
        int j = o & 7, ch = o >> 3;
        int n = ch % 96, kt = ch / 96;
        W2R[o] = f2bf(W2[(kt * 8 + j) * 96 + n]);
    }
}

// ---------------------------------------------------------------------------
// CSR build: fused histogram+rank -> block scan -> top scan -> fixup -> scatter.
__global__ void rank0_kernel(const int* __restrict__ eidx, int* __restrict__ cnt,
                             int* __restrict__ pos0) {
    int e = blockIdx.x * 256 + threadIdx.x;
    if (e < N_EDGES) pos0[e] = atomicAdd(&cnt[eidx[N_EDGES + e]], 1);
}

__global__ void scan_block(const int* __restrict__ cnt, int* __restrict__ start,
                           int* __restrict__ bsum) {
    __shared__ int tmp[256];
    const int t = threadIdx.x, i = blockIdx.x * 256 + t;
    int v = (i < N_NODES) ? cnt[i] : 0;
    tmp[t] = v; __syncthreads();
    #pragma unroll
    for (int off = 1; off < 256; off <<= 1) {
        int add = (t >= off) ? tmp[t - off] : 0;
        __syncthreads();
        tmp[t] += add;
        __syncthreads();
    }
    if (i < N_NODES) start[i] = tmp[t] - v;
    if (t == 255) bsum[blockIdx.x] = tmp[255];
}

__global__ void scan_top(const int* __restrict__ bsum, int* __restrict__ boff,
                         int* __restrict__ start) {
    __shared__ int tmp[256];
    const int t = threadIdx.x;
    int v = (t < NBLK) ? bsum[t] : 0;
    tmp[t] = v; __syncthreads();
    #pragma unroll
    for (int off = 1; off < 256; off <<= 1) {
        int add = (t >= off) ? tmp[t - off] : 0;
        __syncthreads();
        tmp[t] += add;
        __syncthreads();
    }
    if (t < NBLK) boff[t] = tmp[t] - v;
    if (t == 255) start[N_NODES] = tmp[255];
}

__global__ void scan_fix(int* __restrict__ start, const int* __restrict__ boff) {
    const int t = threadIdx.x, i = blockIdx.x * 256 + t;
    if (i < N_NODES) start[i] += boff[blockIdx.x];
}

__global__ void scatter_kernel(const int* __restrict__ eidx, const int* __restrict__ start,
                               const int* __restrict__ pos0, int4* __restrict__ srt) {
    int e = blockIdx.x * 256 + threadIdx.x;
    if (e < N_EDGES) {
        int r = eidx[e];
        int c = eidx[N_EDGES + e];
        int slot = start[c] + pos0[e];
        srt[slot] = make_int4(e, r, c, 0);
    }
}

// ---------------------------------------------------------------------------
// Main fused kernel, PERSISTENT blocks with LDS-resident weights.
// R5 diagnosis: every wave streamed 88 KB of weights through the 32 KB L1
// (4.4 GB/CU total) -> L1-miss machinery saturated; time invariant to
// occupancy. Here: 256 blocks (1/CU) x 8 waves. Weights staged to LDS once
// per block (one __syncthreads), then each wave independently processes 25
// contiguous sorted 16-edge tiles in its private 8 KB LDS slice, with only
// wave-local lgkmcnt fences (no cross-wave waits). rot kept in registers
// across stage1->stage4. LDS = 64K (W1) + 24K (W2) + 8x8K (tiles) = 152 KB.
__global__ __launch_bounds__(512, 2)
void eq_main_sorted(const float* __restrict__ x_scalar, const float* __restrict__ x_rot,
                    const float* __restrict__ dist, const float* __restrict__ rot,
                    const unsigned short* __restrict__ W1R, const float* __restrict__ b1,
                    const unsigned short* __restrict__ W2R, const float* __restrict__ b2,
                    const int4* __restrict__ srt, unsigned int* __restrict__ msg)
{
    __shared__ unsigned char SH[155648];
    unsigned char* W1L = SH;                         // 65536 B
    unsigned char* W2L = SH + 65536;                 // 24576 B

    const int tid  = threadIdx.x;                    // 0..511
    const int wave = tid >> 6, lane = tid & 63;
    unsigned char* tile = SH + 90112 + wave * 8192;  // wave-private 8 KB

    // ---- one-time: stage rearranged weights to LDS (linear copy) ----------
    {
        const uint4* g1 = (const uint4*)W1R;  uint4* l1 = (uint4*)W1L;
        #pragma unroll
        for (int i = 0; i < 8; ++i) l1[i * 512 + tid] = g1[i * 512 + tid];
        const uint4* g2 = (const uint4*)W2R;  uint4* l2 = (uint4*)W2L;
        #pragma unroll
        for (int i = 0; i < 3; ++i) l2[i * 512 + tid] = g2[i * 512 + tid];
    }
    __syncthreads();                                 // the ONLY block barrier

    const int eL = lane >> 2, p = lane & 3;          // edge-local 0..15, quarter
    const int lrow = lane & 15, quad = lane >> 4;

    const int g  = blockIdx.x * 8 + wave;            // global wave id, 0..2047
    int t0 = g * TPW, t1 = t0 + TPW;
    if (t1 > NTILES) t1 = NTILES;

    for (int t = t0; t < t1; ++t) {
        const int slot = t * 16 + eL;
        const int4 erc = srt[slot];
        const int e = erc.x, r = erc.y, c = erc.z;

        float rb[16];                                // edge rotation, kept to stage 4
        {
            const float4* rp = (const float4*)(rot + (size_t)e * 16);
            #pragma unroll
            for (int i = 0; i < 4; ++i) ((float4*)rb)[i] = rp[i];
        }

        // ---------- stage 1: build 16x256 bf16 msg tile (swizzled) ----------
        {
            const float *baseA, *baseB; bool rotA, rotB;
            if (p == 0)      { baseA = x_scalar + (size_t)c * NSC;     rotA = false;
                               baseB = x_rot    + (size_t)c * 64;      rotB = true;  }
            else if (p == 1) { baseA = x_rot    + (size_t)c * 64 + 32; rotA = true;
                               baseB = x_scalar + (size_t)r * NSC;     rotB = false; }
            else if (p == 2) { baseA = x_rot    + (size_t)r * 64;      rotA = true;
                               baseB = x_rot    + (size_t)r * 64 + 32; rotB = true;  }
            else             { baseA = dist     + (size_t)e * 64;      rotA = false;
                               baseB = dist     + (size_t)e * 64 + 32; rotB = false; }

            #pragma unroll
            for (int i = 0; i < 8; ++i) {
                const float* src  = (i < 4) ? (baseA + i * 8) : (baseB + (i - 4) * 8);
                const bool  isrot = (i < 4) ? rotA : rotB;
                float4 v0 = ((const float4*)src)[0], v1 = ((const float4*)src)[1];
                float x[8] = { v0.x, v0.y, v0.z, v0.w, v1.x, v1.y, v1.z, v1.w };
                u16x8 tt;
                #pragma unroll
                for (int k = 0; k < 4; ++k) {
                    float a0 = x[2 * k], a1 = x[2 * k + 1];
                    float r0 = a0 * rb[4 * k]     + a1 * rb[4 * k + 1];
                    float r1 = a0 * rb[4 * k + 2] + a1 * rb[4 * k + 3];
                    tt[2 * k]     = f2bf(isrot ? r0 : a0);
                    tt[2 * k + 1] = f2bf(isrot ? r1 : a1);
                }
                const int ci = p * 8 + i;
                *(u16x8*)&tile[(eL << 9) + ((ci * 16) ^ ((eL & 7) << 4))] = tt;
            }
        }
        WAVE_SYNC();                                 // tile writes -> visible

        // ---------- stage 2: GEMM1  msg(16x256) @ W1(256x128) ---------------
        f32x4 acc[8];
        #pragma unroll
        for (int j = 0; j < 8; ++j) acc[j] = (f32x4){0.f, 0.f, 0.f, 0.f};
        #pragma unroll
        for (int kk = 0; kk < 8; ++kk) {
            bf16x8 a = *(const bf16x8*)&tile[(lrow << 9) +
                                             ((kk * 64 + quad * 16) ^ ((lrow & 7) << 4))];
            const unsigned char* wb = W1L + ((kk * 4 + quad) * 128) * 16;
            #pragma unroll
            for (int j = 0; j < 8; ++j) {
                bf16x8 b = *(const bf16x8*)(wb + (j * 16 + lrow) * 16);
                acc[j] = __builtin_amdgcn_mfma_f32_16x16x32_bf16(a, b, acc[j], 0, 0, 0);
            }
        }
        WAVE_SYNC();                                 // drain A reads before H writes

        unsigned short* H16 = (unsigned short*)tile;
        #pragma unroll
        for (int j = 0; j < 8; ++j) {
            const int n = j * 16 + lrow;
            const float bv = b1[n];                  // global, L1-cached (512 B)
            #pragma unroll
            for (int rr = 0; rr < 4; ++rr) {
                const int m = quad * 4 + rr;
                float v = acc[j][rr] + bv;
                float hv = v / (1.0f + __expf(-v));
                H16[m * LDH + n] = f2bf(hv);
            }
        }
        WAVE_SYNC();                                 // H writes -> visible

        // ---------- stage 3: GEMM2  h(16x128) @ W2(128x96) ------------------
        f32x4 acc2[6];
        #pragma unroll
        for (int j = 0; j < 6; ++j) acc2[j] = (f32x4){0.f, 0.f, 0.f, 0.f};
        #pragma unroll
        for (int kk = 0; kk < 4; ++kk) {
            bf16x8 a = *(const bf16x8*)&H16[lrow * LDH + kk * 32 + quad * 8];
            const unsigned char* wb = W2L + ((kk * 4 + quad) * 96) * 16;
            #pragma unroll
            for (int j = 0; j < 6; ++j) {
                bf16x8 b = *(const bf16x8*)(wb + (j * 16 + lrow) * 16);
                acc2[j] = __builtin_amdgcn_mfma_f32_16x16x32_bf16(a, b, acc2[j], 0, 0, 0);
            }
        }
        WAVE_SYNC();                                 // drain H reads before XO writes

        float* XOf = (float*)tile;
        #pragma unroll
        for (int j = 0; j < 6; ++j) {
            const int n = j * 16 + lrow;
            const float bv = b2[n];
            #pragma unroll
            for (int rr = 0; rr < 4; ++rr) {
                const int m = quad * 4 + rr;
                XOf[m * LDXO + n] = acc2[j][rr] + bv;
            }
        }
        WAVE_SYNC();                                 // XO writes -> visible

        // ---------- stage 4: forward-rotate + emit sorted bf16 row ----------
        {
            const float* xo = XOf + eL * LDXO;
            unsigned int buf[12];
            #pragma unroll
            for (int q = 0; q < 12; ++q) {
                const int i = p * 24 + 2 * q;
                float v0 = xo[i], v1 = xo[i + 1];
                if (i >= NSC) {
                    const int k = ((i - NSC) >> 1) & 3;
                    float a0 = v0, a1 = v1;
                    v0 = a0 * rb[4 * k + 0] + a1 * rb[4 * k + 2];
                    v1 = a0 * rb[4 * k + 1] + a1 * rb[4 * k + 3];
                }
                buf[q] = (unsigned int)f2bf(v0) | ((unsigned int)f2bf(v1) << 16);
            }
            unsigned int* mrow = msg + (size_t)slot * 48 + p * 12;   // contiguous
            *(uint4*)(mrow + 0) = *(uint4*)(buf + 0);
            *(uint4*)(mrow + 4) = *(uint4*)(buf + 4);
            *(uint4*)(mrow + 8) = *(uint4*)(buf + 8);
        }
        WAVE_SYNC();                                 // drain XO reads before next tile
    }
}

// ---------------------------------------------------------------------------
// Fallback (atomic scatter) kernel — only used when the workspace is too
// small for the sorted path. Updated to the rearranged weight layout.
__global__ __launch_bounds__(256, 2)
void eq_main_atomic(const float* __restrict__ x_scalar, const float* __restrict__ x_rot,
                    const int* __restrict__ eidx, const float* __restrict__ dist,
                    const float* __restrict__ rot,
                    const unsigned short* __restrict__ W1R, const float* __restrict__ b1,
                    const unsigned short* __restrict__ W2R, const float* __restrict__ b2,
                    float* __restrict__ out_scalar, float* __restrict__ out_rot)
{
    __shared__ union { unsigned char B[64 * 512]; float XO[64 * LDXO]; } uA;
    __shared__ unsigned short H[64 * LDH];
    __shared__ int colidx[64];

    const int tid = threadIdx.x;
    const int e0  = blockIdx.x * 64;

    {
        const int eL = tid >> 2, p = tid & 3;
        const int e  = e0 + eL;
        if (e < N_EDGES) {
            const int r = eidx[e];
            const int c = eidx[N_EDGES + e];
            if (p == 0) colidx[eL] = c;
            float rb[16];
            {
                const float4* rp = (const float4*)(rot + (size_t)e * 16);
                #pragma unroll
                for (int i = 0; i < 4; ++i) ((float4*)rb)[i] = rp[i];
            }
            const float *baseA, *baseB; bool rotA, rotB;
            if (p == 0)      { baseA = x_scalar + (size_t)c * NSC;     rotA = false;
                               baseB = x_rot    + (size_t)c * 64;      rotB = true;  }
            else if (p == 1) { baseA = x_rot    + (size_t)c * 64 + 32; rotA = true;
                               baseB = x_scalar + (size_t)r * NSC;     rotB = false; }
            else if (p == 2) { baseA = x_rot    + (size_t)r * 64;      rotA = true;
                               baseB = x_rot    + (size_t)r * 64 + 32; rotB = true;  }
            else             { baseA = dist     + (size_t)e * 64;      rotA = false;
                               baseB = dist     + (size_t)e * 64 + 32; rotB = false; }
            #pragma unroll
            for (int i = 0; i < 8; ++i) {
                const float* src  = (i < 4) ? (baseA + i * 8) : (baseB + (i - 4) * 8);
                const bool  isrot = (i < 4) ? rotA : rotB;
                float4 v0 = ((const float4*)src)[0], v1 = ((const float4*)src)[1];
                float x[8] = { v0.x, v0.y, v0.z, v0.w, v1.x, v1.y, v1.z, v1.w };
                u16x8 tt;
                #pragma unroll
                for (int k = 0; k < 4; ++k) {
                    float a0 = x[2 * k], a1 = x[2 * k + 1];
                    float r0 = a0 * rb[4 * k]     + a1 * rb[4 * k + 1];
                    float r1 = a0 * rb[4 * k + 2] + a1 * rb[4 * k + 3];
                    tt[2 * k]     = f2bf(isrot ? r0 : a0);
                    tt[2 * k + 1] = f2bf(isrot ? r1 : a1);
                }
                const int ci = p * 8 + i;
                *(u16x8*)&uA.B[(eL << 9) + ((ci * 16) ^ ((eL & 7) << 4))] = tt;
            }
        }
    }
    __syncthreads();

    const int lane = tid & 63, wave = tid >> 6;
    const int lrow = lane & 15, quad = lane >> 4;
    const int m0 = wave * 16;

    {
        f32x4 acc[8];
        #pragma unroll
        for (int j = 0; j < 8; ++j) acc[j] = (f32x4){0.f, 0.f, 0.f, 0.f};
        #pragma unroll
        for (int kk = 0; kk < 8; ++kk) {
            bf16x8 a = *(const bf16x8*)&uA.B[((m0 + lrow) << 9) +
                                             ((kk * 64 + quad * 16) ^ ((lrow & 7) << 4))];
            const unsigned short* wb = W1R + (size_t)(kk * 4 + quad) * 1024;
            #pragma unroll
            for (int j = 0; j < 8; ++j) {
                bf16x8 b = *(const bf16x8*)(wb + (j * 16 + lrow) * 8);
                acc[j] = __builtin_amdgcn_mfma_f32_16x16x32_bf16(a, b, acc[j], 0, 0, 0);
            }
        }
        __syncthreads();
        #pragma unroll
        for (int j = 0; j < 8; ++j) {
            const int n = j * 16 + lrow;
            const float bv = b1[n];
            #pragma unroll
            for (int rr = 0; rr < 4; ++rr) {
                const int m = m0 + quad * 4 + rr;
                float v = acc[j][rr] + bv;
                float hv = v / (1.0f + __expf(-v));
                H[m * LDH + n] = f2bf(hv);
            }
        }
    }
    __syncthreads();

    {
        f32x4 acc2[6];
        #pragma unroll
        for (int j = 0; j < 6; ++j) acc2[j] = (f32x4){0.f, 0.f, 0.f, 0.f};
        #pragma unroll
        for (int kk = 0; kk < 4; ++kk) {
            bf16x8 a = *(const bf16x8*)&H[(m0 + lrow) * LDH + kk * 32 + quad * 8];
            const unsigned short* wb = W2R + (size_t)(kk * 4 + quad) * 768;
            #pragma unroll
            for (int j = 0; j < 6; ++j) {
                bf16x8 b = *(const bf16x8*)(wb + (j * 16 + lrow) * 8);
                acc2[j] = __builtin_amdgcn_mfma_f32_16x16x32_bf16(a, b, acc2[j], 0, 0, 0);
            }
        }
        __syncthreads();
        #pragma unroll
        for (int j = 0; j < 6; ++j) {
            const int n = j * 16 + lrow;
            const float bv = b2[n];
            #pragma unroll
            for (int rr = 0; rr < 4; ++rr) {
                const int m = m0 + quad * 4 + rr;
                float v = acc2[j][rr] + bv;
                if (j < 2) {
                    if (e0 + m < N_EDGES)
                        atomicAdd(&out_scalar[(size_t)colidx[m] * NSC + n], v);
                } else {
                    uA.XO[m * LDXO + (n - NSC)] = v;
                }
            }
        }
    }
    __syncthreads();

    {
        const int eL = tid >> 2, p = tid & 3;
        const int e  = e0 + eL;
        if (e < N_EDGES) {
            float rb[16];
            {
                const float4* rp = (const float4*)(rot + (size_t)e * 16);
                #pragma unroll
                for (int i = 0; i < 4; ++i) ((float4*)rb)[i] = rp[i];
            }
            const int c = colidx[eL];
            const float* xo = &uA.XO[eL * LDXO];
            float* outp = out_rot + (size_t)c * 64;
            #pragma unroll
            for (int jj = 0; jj < 2; ++jj) {
                const int j = 2 * p + jj;
                #pragma unroll
                for (int k = 0; k < 4; ++k) {
                    float a0 = xo[j * 8 + k * 2], a1 = xo[j * 8 + k * 2 + 1];
                    atomicAdd(&outp[j * 8 + k * 2 + 0], a0 * rb[4 * k + 0] + a1 * rb[4 * k + 2]);
                    atomicAdd(&outp[j * 8 + k * 2 + 1], a0 * rb[4 * k + 1] + a1 * rb[4 * k + 3]);
                }
            }
        }
    }
}

// ---------------------------------------------------------------------------
// Gather: one wave per node, stream contiguous sorted message rows, fp32 acc.
__global__ __launch_bounds__(256)
void gather_kernel(const unsigned int* __restrict__ msg, const int* __restrict__ start,
                   float* __restrict__ out_scalar, float* __restrict__ out_rot) {
    const int wave = threadIdx.x >> 6, lane = threadIdx.x & 63;
    const int n = blockIdx.x * 4 + wave;
    if (n >= N_NODES) return;
    const int s = start[n], e = start[n + 1];
    if (lane < 48) {
        float a0 = 0.f, a1 = 0.f;
        const unsigned int* p = msg + (size_t)s * 48 + lane;
        int i = s;
        for (; i + 1 < e; i += 2) {
            unsigned int u0 = p[0], u1 = p[48];
            p += 96;
            a0 += bflo(u0) + bflo(u1);
            a1 += bfhi(u0) + bfhi(u1);
        }
        if (i < e) { unsigned int u = p[0]; a0 += bflo(u); a1 += bfhi(u); }
        const int col = lane * 2;
        float2 r = make_float2(a0, a1);
        if (col < NSC) *(float2*)(out_scalar + (size_t)n * NSC + col) = r;
        else           *(float2*)(out_rot   + (size_t)n * 64 + (col - NSC)) = r;
    }
}

// ---------------------------------------------------------------------------
extern "C" void kernel_launch(void* const* d_in, const int* in_sizes, int n_in,
                              void* d_out, int out_size, void* d_ws, size_t ws_size,
                              hipStream_t stream) {
    const float* x_scalar = (const float*)d_in[0];
    const float* x_rot    = (const float*)d_in[1];
    const int*   eidx     = (const int*)d_in[2];
    const float* dist     = (const float*)d_in[3];
    const float* rot      = (const float*)d_in[4];
    const float* W1       = (const float*)d_in[5];
    const float* b1       = (const float*)d_in[6];
    const float* W2       = (const float*)d_in[7];
    const float* b2       = (const float*)d_in[8];
    float* out        = (float*)d_out;
    float* out_rot    = out + (size_t)N_NODES * NSC;

    // workspace bump allocator (256B aligned)
    uintptr_t base = (uintptr_t)d_ws;
    auto alloc = [&](size_t bytes) {
        uintptr_t p = base; base += (bytes + 255) & ~(size_t)255; return p;
    };
    unsigned short* W1R  = (unsigned short*)alloc(256 * 128 * 2);
    unsigned short* W2R  = (unsigned short*)alloc(128 * 96 * 2);
    int*            cnt  = (int*)alloc(N_NODES * 4);
    int*            start= (int*)alloc((N_NODES + 1) * 4);
    int*            bsum = (int*)alloc(NBLK * 4);
    int*            boff = (int*)alloc(NBLK * 4);
    int*            pos0 = (int*)alloc((size_t)N_EDGES * 4);
    int4*           srt  = (int4*)alloc((size_t)N_EDGES * 16);
    unsigned int*   msg  = (unsigned int*)alloc((size_t)N_EDGES * 48 * 4);
    const size_t needed = base - (uintptr_t)d_ws;

    prep_weights<<<128, 256, 0, stream>>>(W1, W2, W1R, W2R);

    if (ws_size >= needed) {
        hipMemsetAsync(cnt, 0, N_NODES * 4, stream);
        rank0_kernel<<<N_EDGES / 256, 256, 0, stream>>>(eidx, cnt, pos0);
        scan_block<<<NBLK, 256, 0, stream>>>(cnt, start, bsum);
        scan_top<<<1, 256, 0, stream>>>(bsum, boff, start);
        scan_fix<<<NBLK, 256, 0, stream>>>(start, boff);
        scatter_kernel<<<N_EDGES / 256, 256, 0, stream>>>(eidx, start, pos0, srt);
        eq_main_sorted<<<256, 512, 0, stream>>>(
            x_scalar, x_rot, dist, rot, W1R, b1, W2R, b2, srt, msg);
        gather_kernel<<<(N_NODES + 3) / 4, 256, 0, stream>>>(msg, start, out, out_rot);
    } else {
        // fallback: atomic scatter
        hipMemsetAsync(d_out, 0, (size_t)out_size * sizeof(float), stream);
        eq_main_atomic<<<N_EDGES / 64, 256, 0, stream>>>(
            x_scalar, x_rot, eidx, dist, rot, W1R, b1, W2R, b2,
            out, out_rot);
    }
}